// Round 4
// baseline (866.580 us; speedup 1.0000x reference)
//
#include <hip/hip_runtime.h>

#define L_LEN 512
#define D_DIM 4096
#define H_NUM 8
#define B_NUM 16
#define TOPK  12

// ---------------------------------------------------------------------------
// Stage A: per-channel circular cross-correlation + top-12 + softmax.
// grid = B*H*64 blocks of 512 threads = 8 waves; ONE channel per wave.
// Lane l owns taus 8l..8l+7. k reads are wave-uniform (broadcast, no
// conflicts). q reads: 16B-group G = W>>2 stored at G ^ ((G>>3)&1):
// every 8 consecutive lanes cover all 8 bank-groups. Rotating 32-slot
// register window (compile-time indices) -> 4 q-reads + 4 k-reads +
// 256 fmaf per 32 t.
// ---------------------------------------------------------------------------

// physical address of 16B-aligned logical word W within a channel row
#define QADDR(W) (qc + (((((W) >> 2) ^ (((W) >> 5) & 1)) << 2) | ((W) & 3)))

#define ITER(P, I) do {                                                      \
    const int t0 = (I) * 16;                                                 \
    const float4 r0_ = *(const float4*)QADDR(tau0 + t0 + 32);                \
    const float4 r1_ = *(const float4*)QADDR(tau0 + t0 + 36);                \
    const float4 r2_ = *(const float4*)QADDR(tau0 + t0 + 40);                \
    const float4 r3_ = *(const float4*)QADDR(tau0 + t0 + 44);                \
    const float4 ka_ = *(const float4*)(kc + t0);                            \
    const float4 kb_ = *(const float4*)(kc + t0 + 4);                        \
    {                                                                        \
      const float kk[8] = {ka_.x,ka_.y,ka_.z,ka_.w, kb_.x,kb_.y,kb_.z,kb_.w};\
      _Pragma("unroll")                                                      \
      for (int tt = 0; tt < 8; ++tt)                                         \
        _Pragma("unroll")                                                    \
        for (int ii = 0; ii < 8; ++ii)                                       \
          acc[ii] = fmaf(qb[((P) + ii + tt) & 31], kk[tt], acc[ii]);         \
    }                                                                        \
    const float4 kc_ = *(const float4*)(kc + t0 + 8);                        \
    const float4 kd_ = *(const float4*)(kc + t0 + 12);                       \
    {                                                                        \
      const float kk[8] = {kc_.x,kc_.y,kc_.z,kc_.w, kd_.x,kd_.y,kd_.z,kd_.w};\
      _Pragma("unroll")                                                      \
      for (int tt = 0; tt < 8; ++tt)                                         \
        _Pragma("unroll")                                                    \
        for (int ii = 0; ii < 8; ++ii)                                       \
          acc[ii] = fmaf(qb[((P) + 8 + ii + tt) & 31], kk[tt], acc[ii]);     \
    }                                                                        \
    qb[(P)+ 0]=r0_.x; qb[(P)+ 1]=r0_.y; qb[(P)+ 2]=r0_.z; qb[(P)+ 3]=r0_.w;  \
    qb[(P)+ 4]=r1_.x; qb[(P)+ 5]=r1_.y; qb[(P)+ 6]=r1_.z; qb[(P)+ 7]=r1_.w;  \
    qb[(P)+ 8]=r2_.x; qb[(P)+ 9]=r2_.y; qb[(P)+10]=r2_.z; qb[(P)+11]=r2_.w;  \
    qb[(P)+12]=r3_.x; qb[(P)+13]=r3_.y; qb[(P)+14]=r3_.z; qb[(P)+15]=r3_.w;  \
  } while (0)

__global__ __launch_bounds__(512, 4) void corr_topk_kernel(
    const float* __restrict__ Q, const float* __restrict__ K,
    float* __restrict__ ws_w, int* __restrict__ ws_i)
{
  __shared__ float qs[8][1056];   // 33792 B, XOR-group swizzled, dup + wrap
  __shared__ float ks[8][512];    // 16384 B, linear  (total 50176 B <= 64K)

  const int tid = threadIdx.x;
  const int bid = blockIdx.x;
  // chunked XCD remap: all 64 blocks of one bh on one XCD (L2 line merge)
  const int work = (bid & 7) * 1024 + (bid >> 3);
  const int bh   = work >> 6;
  const int c0   = (work & 63) * 8;

  const size_t base = (size_t)(bh >> 3) * (size_t)(L_LEN * D_DIM)
                    + (size_t)(bh & 7) * 512 + c0;

  // staging: thread loads float4 = 4 channels of one row t
  #pragma unroll
  for (int rep = 0; rep < 2; ++rep) {
    const int idx  = rep * 512 + tid;       // 0..1023
    const int t    = idx >> 1;
    const int half = idx & 1;
    const float4 qv = *(const float4*)(Q + base + (size_t)t * D_DIM + half * 4);
    const float4 kv = *(const float4*)(K + base + (size_t)t * D_DIM + half * 4);
    // swizzle(t+512) == swizzle(t)+512 (XOR bit is group-bit3, unchanged)
    const int pw = ((((t >> 2) ^ ((t >> 5) & 1)) << 2) | (t & 3));
    const int cb = half * 4;
    const float qa[4] = {qv.x, qv.y, qv.z, qv.w};
    const float ka[4] = {kv.x, kv.y, kv.z, kv.w};
    #pragma unroll
    for (int j = 0; j < 4; ++j) {
      qs[cb + j][pw]       = qa[j];
      qs[cb + j][pw + 512] = qa[j];
      ks[cb + j][t]        = ka[j];
    }
    if (t < 32) {                           // wrap region [1024,1056)
      #pragma unroll
      for (int j = 0; j < 4; ++j) qs[cb + j][pw + 1024] = qa[j];
    }
  }
  __syncthreads();

  const int wv   = __builtin_amdgcn_readfirstlane(tid >> 6);
  const int lane = tid & 63;
  const int tau0 = lane * 8;

  const float* __restrict__ qc = qs[wv];
  const float* __restrict__ kc = ks[wv];

  float acc[8];
  #pragma unroll
  for (int i = 0; i < 8; ++i) acc[i] = 0.f;

  float qb[32];
  #pragma unroll
  for (int x = 0; x < 8; ++x) {             // prologue: logical [tau0,tau0+32)
    const float4 v = *(const float4*)QADDR(tau0 + 4 * x);
    qb[4*x] = v.x; qb[4*x+1] = v.y; qb[4*x+2] = v.z; qb[4*x+3] = v.w;
  }

  #pragma unroll 1
  for (int i = 0; i < 32; i += 2) {
    ITER(0, i);
    ITER(16, i + 1);
  }

  // ---- top-12 via repeated wave-wide argmax (tie-break: smaller index)
  float bv[TOPK]; int bi[TOPK];
  #pragma unroll
  for (int s = 0; s < TOPK; ++s) {
    float lv = acc[0]; int li = 0;
    #pragma unroll
    for (int i = 1; i < 8; ++i) if (acc[i] > lv) { lv = acc[i]; li = i; }
    int gi = tau0 + li;
    #pragma unroll
    for (int off = 32; off >= 1; off >>= 1) {
      const float ov = __shfl_xor(lv, off, 64);
      const int   oi = __shfl_xor(gi, off, 64);
      if (ov > lv || (ov == lv && oi < gi)) { lv = ov; gi = oi; }
    }
    bv[s] = lv; bi[s] = gi;
    const int slot = gi - tau0;
    #pragma unroll
    for (int i = 0; i < 8; ++i) acc[i] = (slot == i) ? -3.4e38f : acc[i];
  }

  float e[TOPK]; float sum = 0.f;
  #pragma unroll
  for (int s = 0; s < TOPK; ++s) { e[s] = expf(bv[s] - bv[0]); sum += e[s]; }
  const float inv = 1.f / sum;

  if (lane == 0) {
    const int g = (bh * 512 + c0 + wv) * TOPK;
    #pragma unroll
    for (int s = 0; s < TOPK; ++s) { ws_w[g + s] = e[s] * inv; ws_i[g + s] = bi[s]; }
  }
}

// ---------------------------------------------------------------------------
// Stage B (true verbatim round-1 passing version, ~211 us): block =
// (b, 32-column window of D), 512 threads, vs staged in descending quarters
// (r = min(r0+t,511) >= t -> later stagings write strictly lower rows than
// any concurrent reader; 1 barrier/phase; next quarter's loads issued
// before the barrier, raw s_barrier keeps them in flight).
// LDS = 65536 B exactly (the 64 KiB static limit — do not exceed).
// ---------------------------------------------------------------------------
__global__ __launch_bounds__(512, 4) void gather_kernel(
    const float* __restrict__ V, const float* __restrict__ ws_w,
    const int* __restrict__ ws_i, float* __restrict__ out)
{
  __shared__ float vs[512][32];   // 65536 B

  const int tid = threadIdx.x;
  const int bid = blockIdx.x;
  const int work = (bid & 7) * 256 + (bid >> 3);   // chunked XCD remap
  const int b  = work >> 7;
  const int dg = work & 127;
  const int d0 = dg * 32;
  const int h  = d0 >> 9;
  const int c0 = d0 & 511;

  const size_t vcol = (size_t)b * (size_t)(L_LEN * D_DIM) + d0;

  const int cl   = tid & 31;
  const int tsub = tid >> 5;              // 0..15

  float4 stga, stgb;
  const int e0 = tid, e1 = 512 + tid;
  const int ra0 = e0 >> 3, qa0 = (e0 & 7) * 4;   // rows 0..63 of quarter
  const int rb0 = e1 >> 3, qb0 = (e1 & 7) * 4;   // rows 64..127 of quarter

  // prologue: issue loads for phase 3 (rows 384..511)
  stga = *(const float4*)(V + vcol + (size_t)(384 + ra0) * D_DIM + qa0);
  stgb = *(const float4*)(V + vcol + (size_t)(384 + rb0) * D_DIM + qb0);

  const int g = ((b * 8 + h) * 512 + c0 + cl) * TOPK;
  float w[TOPK]; int r0[TOPK];
  #pragma unroll
  for (int s = 0; s < TOPK; ++s) { w[s] = ws_w[g + s]; r0[s] = ws_i[g + s]; }

  const size_t ob = vcol + cl;

  #pragma unroll 1
  for (int ph = 3; ph >= 0; --ph) {
    *(float4*)(&vs[ph * 128 + ra0][qa0]) = stga;
    *(float4*)(&vs[ph * 128 + rb0][qb0]) = stgb;
    if (ph > 0) {  // issue next quarter early; in flight across the barrier
      stga = *(const float4*)(V + vcol + (size_t)((ph - 1) * 128 + ra0) * D_DIM + qa0);
      stgb = *(const float4*)(V + vcol + (size_t)((ph - 1) * 128 + rb0) * D_DIM + qb0);
    }
    asm volatile("s_waitcnt lgkmcnt(0)" ::: "memory");
    __builtin_amdgcn_s_barrier();
    asm volatile("" ::: "memory");

    // compute outputs t in [ph*128, (ph+1)*128)
    #pragma unroll
    for (int k8 = 0; k8 < 8; ++k8) {
      const int t = ph * 128 + (k8 << 4) + tsub;
      float a = 0.f;
      #pragma unroll
      for (int s = 0; s < TOPK; ++s) {
        int r = r0[s] + t;
        r = r > (L_LEN - 1) ? (L_LEN - 1) : r;
        a = fmaf(w[s], vs[r][cl], a);       // bank = cl: scatter-immune
      }
      out[ob + (size_t)t * D_DIM] = a;
    }
  }
}

extern "C" void kernel_launch(void* const* d_in, const int* in_sizes, int n_in,
                              void* d_out, int out_size, void* d_ws, size_t ws_size,
                              hipStream_t stream)
{
  const float* Q = (const float*)d_in[0];
  const float* K = (const float*)d_in[1];
  const float* V = (const float*)d_in[2];
  float* out = (float*)d_out;

  float* ws_w = (float*)d_ws;
  int*   ws_i = (int*)((char*)d_ws + (size_t)B_NUM * H_NUM * 512 * TOPK * sizeof(float));

  corr_topk_kernel<<<dim3(B_NUM * H_NUM * 64), dim3(512), 0, stream>>>(Q, K, ws_w, ws_i);
  gather_kernel<<<dim3(B_NUM * H_NUM * 16), dim3(512), 0, stream>>>(V, ws_w, ws_i, out);
}

// Round 6
// 854.086 us; speedup vs baseline: 1.0146x; 1.0146x over previous
//
#include <hip/hip_runtime.h>

#define L_LEN 512
#define D_DIM 4096
#define H_NUM 8
#define B_NUM 16
#define TOPK  12

// ---------------------------------------------------------------------------
// Stage A: per-channel circular cross-correlation + top-12 + softmax.
// grid = B*H*64 blocks of 512 threads = 8 waves; ONE channel per wave.
// Lane l owns taus 8l..8l+7. k reads are wave-uniform (broadcast).
// q LDS layout is swizzled at 16B-GROUP granularity: logical group G
// stored at G ^ ((G>>3)&1). All LDS accesses are indexed in float4 units
// on float4* (16B alignment provable -> ds_read_b128, NOT 4x b32).
// Every 8 consecutive lanes (G = 2*lane + u) cover all 8 bank-groups for
// any u -> conflict-free b128. Rotating 32-slot register window
// (compile-time indices) -> 4 q-reads + 4 k-reads + 256 fmaf per 16 t.
// ---------------------------------------------------------------------------

#define QLD(GI) (qc4[(GI) ^ (((GI) >> 3) & 1)])

#define ITER(P, I) do {                                                      \
    const int gb = 4 * (I) + 8;                                              \
    const float4 r0_ = QLD(gq + gb);                                         \
    const float4 r1_ = QLD(gq + gb + 1);                                     \
    const float4 r2_ = QLD(gq + gb + 2);                                     \
    const float4 r3_ = QLD(gq + gb + 3);                                     \
    const float4 ka_ = kc4[4 * (I)];                                         \
    const float4 kb_ = kc4[4 * (I) + 1];                                     \
    {                                                                        \
      const float kk[8] = {ka_.x,ka_.y,ka_.z,ka_.w, kb_.x,kb_.y,kb_.z,kb_.w};\
      _Pragma("unroll")                                                      \
      for (int tt = 0; tt < 8; ++tt)                                         \
        _Pragma("unroll")                                                    \
        for (int ii = 0; ii < 8; ++ii)                                       \
          acc[ii] = fmaf(qb[((P) + ii + tt) & 31], kk[tt], acc[ii]);         \
    }                                                                        \
    const float4 kc_ = kc4[4 * (I) + 2];                                     \
    const float4 kd_ = kc4[4 * (I) + 3];                                     \
    {                                                                        \
      const float kk[8] = {kc_.x,kc_.y,kc_.z,kc_.w, kd_.x,kd_.y,kd_.z,kd_.w};\
      _Pragma("unroll")                                                      \
      for (int tt = 0; tt < 8; ++tt)                                         \
        _Pragma("unroll")                                                    \
        for (int ii = 0; ii < 8; ++ii)                                       \
          acc[ii] = fmaf(qb[((P) + 8 + ii + tt) & 31], kk[tt], acc[ii]);     \
    }                                                                        \
    qb[(P)+ 0]=r0_.x; qb[(P)+ 1]=r0_.y; qb[(P)+ 2]=r0_.z; qb[(P)+ 3]=r0_.w;  \
    qb[(P)+ 4]=r1_.x; qb[(P)+ 5]=r1_.y; qb[(P)+ 6]=r1_.z; qb[(P)+ 7]=r1_.w;  \
    qb[(P)+ 8]=r2_.x; qb[(P)+ 9]=r2_.y; qb[(P)+10]=r2_.z; qb[(P)+11]=r2_.w;  \
    qb[(P)+12]=r3_.x; qb[(P)+13]=r3_.y; qb[(P)+14]=r3_.z; qb[(P)+15]=r3_.w;  \
  } while (0)

__global__ __launch_bounds__(512, 4) void corr_topk_kernel(
    const float* __restrict__ Q, const float* __restrict__ K,
    float* __restrict__ ws_w, int* __restrict__ ws_i)
{
  __shared__ __align__(16) float qs[8][1056];  // 33792 B, group-swizzled
  __shared__ __align__(16) float ks[8][512];   // 16384 B, linear

  const int tid = threadIdx.x;
  const int bid = blockIdx.x;
  // chunked XCD remap: all 64 blocks of one bh on one XCD (L2 line merge)
  const int work = (bid & 7) * 1024 + (bid >> 3);
  const int bh   = work >> 6;
  const int c0   = (work & 63) * 8;

  const size_t base = (size_t)(bh >> 3) * (size_t)(L_LEN * D_DIM)
                    + (size_t)(bh & 7) * 512 + c0;

  // staging: thread loads float4 = 4 channels of one row t
  #pragma unroll
  for (int rep = 0; rep < 2; ++rep) {
    const int idx  = rep * 512 + tid;       // 0..1023
    const int t    = idx >> 1;
    const int half = idx & 1;
    const float4 qv = *(const float4*)(Q + base + (size_t)t * D_DIM + half * 4);
    const float4 kv = *(const float4*)(K + base + (size_t)t * D_DIM + half * 4);
    // physical word: group (t>>2) ^ ((t>>5)&1), word-in-group t&3.
    // swizzle(t+512) = swizzle(t)+512, swizzle(t+1024) = swizzle(t)+1024.
    const int pw = ((((t >> 2) ^ ((t >> 5) & 1)) << 2) | (t & 3));
    const int cb = half * 4;
    const float qa[4] = {qv.x, qv.y, qv.z, qv.w};
    const float ka[4] = {kv.x, kv.y, kv.z, kv.w};
    #pragma unroll
    for (int j = 0; j < 4; ++j) {
      qs[cb + j][pw]       = qa[j];
      qs[cb + j][pw + 512] = qa[j];
      ks[cb + j][t]        = ka[j];
    }
    if (t < 32) {                           // wrap region [1024,1056)
      #pragma unroll
      for (int j = 0; j < 4; ++j) qs[cb + j][pw + 1024] = qa[j];
    }
  }
  __syncthreads();

  const int wv   = __builtin_amdgcn_readfirstlane(tid >> 6);
  const int lane = tid & 63;
  const int tau0 = lane * 8;
  const int gq   = lane * 2;                // logical group of tau0

  const float4* __restrict__ qc4 = (const float4*)qs[wv];
  const float4* __restrict__ kc4 = (const float4*)ks[wv];

  float acc[8];
  #pragma unroll
  for (int i = 0; i < 8; ++i) acc[i] = 0.f;

  float qb[32];
  #pragma unroll
  for (int x = 0; x < 8; ++x) {             // prologue: logical [tau0,tau0+32)
    const float4 v = QLD(gq + x);
    qb[4*x] = v.x; qb[4*x+1] = v.y; qb[4*x+2] = v.z; qb[4*x+3] = v.w;
  }

  #pragma unroll 1
  for (int i = 0; i < 32; i += 2) {
    ITER(0, i);
    ITER(16, i + 1);
  }

  // ---- top-12 via repeated wave-wide argmax (tie-break: smaller index)
  float bv[TOPK]; int bi[TOPK];
  #pragma unroll
  for (int s = 0; s < TOPK; ++s) {
    float lv = acc[0]; int li = 0;
    #pragma unroll
    for (int i = 1; i < 8; ++i) if (acc[i] > lv) { lv = acc[i]; li = i; }
    int gi = tau0 + li;
    #pragma unroll
    for (int off = 32; off >= 1; off >>= 1) {
      const float ov = __shfl_xor(lv, off, 64);
      const int   oi = __shfl_xor(gi, off, 64);
      if (ov > lv || (ov == lv && oi < gi)) { lv = ov; gi = oi; }
    }
    bv[s] = lv; bi[s] = gi;
    const int slot = gi - tau0;
    #pragma unroll
    for (int i = 0; i < 8; ++i) acc[i] = (slot == i) ? -3.4e38f : acc[i];
  }

  float e[TOPK]; float sum = 0.f;
  #pragma unroll
  for (int s = 0; s < TOPK; ++s) { e[s] = expf(bv[s] - bv[0]); sum += e[s]; }
  const float inv = 1.f / sum;

  if (lane == 0) {
    const int g = (bh * 512 + c0 + wv) * TOPK;
    #pragma unroll
    for (int s = 0; s < TOPK; ++s) { ws_w[g + s] = e[s] * inv; ws_i[g + s] = bi[s]; }
  }
}

// ---------------------------------------------------------------------------
// Stage B (verbatim passing version, ~240 us): block = (b, 32-column window
// of D), 512 threads, vs staged in descending quarters (r = min(r0+t,511)
// >= t -> later stagings write strictly lower rows than any concurrent
// reader; 1 barrier/phase; next quarter's loads issued before the barrier,
// raw s_barrier keeps them in flight). LDS = 65536 B exactly.
// ---------------------------------------------------------------------------
__global__ __launch_bounds__(512, 4) void gather_kernel(
    const float* __restrict__ V, const float* __restrict__ ws_w,
    const int* __restrict__ ws_i, float* __restrict__ out)
{
  __shared__ __align__(16) float vs[512][32];   // 65536 B

  const int tid = threadIdx.x;
  const int bid = blockIdx.x;
  const int work = (bid & 7) * 256 + (bid >> 3);   // chunked XCD remap
  const int b  = work >> 7;
  const int dg = work & 127;
  const int d0 = dg * 32;
  const int h  = d0 >> 9;
  const int c0 = d0 & 511;

  const size_t vcol = (size_t)b * (size_t)(L_LEN * D_DIM) + d0;

  const int cl   = tid & 31;
  const int tsub = tid >> 5;              // 0..15

  float4 stga, stgb;
  const int e0 = tid, e1 = 512 + tid;
  const int ra0 = e0 >> 3, qa0 = (e0 & 7) * 4;   // rows 0..63 of quarter
  const int rb0 = e1 >> 3, qb0 = (e1 & 7) * 4;   // rows 64..127 of quarter

  // prologue: issue loads for phase 3 (rows 384..511)
  stga = *(const float4*)(V + vcol + (size_t)(384 + ra0) * D_DIM + qa0);
  stgb = *(const float4*)(V + vcol + (size_t)(384 + rb0) * D_DIM + qb0);

  const int g = ((b * 8 + h) * 512 + c0 + cl) * TOPK;
  float w[TOPK]; int r0[TOPK];
  #pragma unroll
  for (int s = 0; s < TOPK; ++s) { w[s] = ws_w[g + s]; r0[s] = ws_i[g + s]; }

  const size_t ob = vcol + cl;

  #pragma unroll 1
  for (int ph = 3; ph >= 0; --ph) {
    *(float4*)(&vs[ph * 128 + ra0][qa0]) = stga;
    *(float4*)(&vs[ph * 128 + rb0][qb0]) = stgb;
    if (ph > 0) {  // issue next quarter early; in flight across the barrier
      stga = *(const float4*)(V + vcol + (size_t)((ph - 1) * 128 + ra0) * D_DIM + qa0);
      stgb = *(const float4*)(V + vcol + (size_t)((ph - 1) * 128 + rb0) * D_DIM + qb0);
    }
    asm volatile("s_waitcnt lgkmcnt(0)" ::: "memory");
    __builtin_amdgcn_s_barrier();
    asm volatile("" ::: "memory");

    // compute outputs t in [ph*128, (ph+1)*128)
    #pragma unroll
    for (int k8 = 0; k8 < 8; ++k8) {
      const int t = ph * 128 + (k8 << 4) + tsub;
      float a = 0.f;
      #pragma unroll
      for (int s = 0; s < TOPK; ++s) {
        int r = r0[s] + t;
        r = r > (L_LEN - 1) ? (L_LEN - 1) : r;
        a = fmaf(w[s], vs[r][cl], a);       // bank = cl: scatter-immune
      }
      out[ob + (size_t)t * D_DIM] = a;
    }
  }
}

extern "C" void kernel_launch(void* const* d_in, const int* in_sizes, int n_in,
                              void* d_out, int out_size, void* d_ws, size_t ws_size,
                              hipStream_t stream)
{
  const float* Q = (const float*)d_in[0];
  const float* K = (const float*)d_in[1];
  const float* V = (const float*)d_in[2];
  float* out = (float*)d_out;

  float* ws_w = (float*)d_ws;
  int*   ws_i = (int*)((char*)d_ws + (size_t)B_NUM * H_NUM * 512 * TOPK * sizeof(float));

  corr_topk_kernel<<<dim3(B_NUM * H_NUM * 64), dim3(512), 0, stream>>>(Q, K, ws_w, ws_i);
  gather_kernel<<<dim3(B_NUM * H_NUM * 16), dim3(512), 0, stream>>>(V, ws_w, ws_i, out);
}

// Round 7
// 836.786 us; speedup vs baseline: 1.0356x; 1.0207x over previous
//
#include <hip/hip_runtime.h>
#include <stdint.h>

#define L_LEN 512
#define D_DIM 4096
#define H_NUM 8
#define B_NUM 16
#define TOPK  12

typedef float f32x4 __attribute__((ext_vector_type(4)));

// ---------------------------------------------------------------------------
// Stage A: per-channel circular cross-correlation + top-12 + softmax.
// grid = B*H*64 blocks of 512 threads = 8 waves; ONE channel per wave.
// Lane l owns taus 8l..8l+7 (window groups G = 2l + 4I + [0,8), mod 128).
// q LDS layout: 16B group G stored at physical group G + (G>>3) (pad 1
// group per 8): every 8 consecutive lanes cover all 8 bank-groups for any
// alignment -> conflict-free ds_read_b128 (worst case one 2-way at the
// mod-128 wrap = free). All hot-loop LDS reads are INLINE-ASM ds_read_b128
// (hipcc was scalarizing C-level float4 LDS reads into 4x ds_read_b32 with
// per-element address math -> 65% of VALU issue was junk; r4/r6 evidence).
// Window = 12 named f32x4 registers, period-3 rotation, zero arrays.
// ---------------------------------------------------------------------------

// physical byte address (within channel row) of logical 16B group G
#define QA(G) (qbase + (((((uint32_t)(G)) & 127u) + ((((uint32_t)(G)) & 127u) >> 3)) << 4))

// acc[ii] += q[ii+tt]*k[tt] for tt=0..3; QA_ = window floats [0..3] at this
// k-quad's t0, QB_ = [4..7], QC_ = [8..11]. Per-acc t-order ascending.
#define MAC4x8(QA_, QB_, QC_, KK_) do {                                       \
    acc0 = fmaf(QA_.x, KK_.x, acc0); acc0 = fmaf(QA_.y, KK_.y, acc0);         \
    acc0 = fmaf(QA_.z, KK_.z, acc0); acc0 = fmaf(QA_.w, KK_.w, acc0);         \
    acc1 = fmaf(QA_.y, KK_.x, acc1); acc1 = fmaf(QA_.z, KK_.y, acc1);         \
    acc1 = fmaf(QA_.w, KK_.z, acc1); acc1 = fmaf(QB_.x, KK_.w, acc1);         \
    acc2 = fmaf(QA_.z, KK_.x, acc2); acc2 = fmaf(QA_.w, KK_.y, acc2);         \
    acc2 = fmaf(QB_.x, KK_.z, acc2); acc2 = fmaf(QB_.y, KK_.w, acc2);         \
    acc3 = fmaf(QA_.w, KK_.x, acc3); acc3 = fmaf(QB_.x, KK_.y, acc3);         \
    acc3 = fmaf(QB_.y, KK_.z, acc3); acc3 = fmaf(QB_.z, KK_.w, acc3);         \
    acc4 = fmaf(QB_.x, KK_.x, acc4); acc4 = fmaf(QB_.y, KK_.y, acc4);         \
    acc4 = fmaf(QB_.z, KK_.z, acc4); acc4 = fmaf(QB_.w, KK_.w, acc4);         \
    acc5 = fmaf(QB_.y, KK_.x, acc5); acc5 = fmaf(QB_.z, KK_.y, acc5);         \
    acc5 = fmaf(QB_.w, KK_.z, acc5); acc5 = fmaf(QC_.x, KK_.w, acc5);         \
    acc6 = fmaf(QB_.z, KK_.x, acc6); acc6 = fmaf(QB_.w, KK_.y, acc6);         \
    acc6 = fmaf(QC_.x, KK_.z, acc6); acc6 = fmaf(QC_.y, KK_.w, acc6);         \
    acc7 = fmaf(QB_.w, KK_.x, acc7); acc7 = fmaf(QC_.x, KK_.y, acc7);         \
    acc7 = fmaf(QC_.y, KK_.z, acc7); acc7 = fmaf(QC_.z, KK_.w, acc7);         \
  } while (0)

// One 16-t step: window = (A0..A3, B0..B3) = groups [gnext-8, gnext);
// loads next 4 q groups into C0..C3 and this step's 16 k floats into
// k0..k3; then 128 FMAs on the current window.
#define ITER3(A0,A1,A2,A3, B0,B1,B2,B3, C0,C1,C2,C3) do {                    \
    const uint32_t a0_ = QA(gnext);                                          \
    const uint32_t a1_ = QA(gnext + 1);                                      \
    const uint32_t a2_ = QA(gnext + 2);                                      \
    const uint32_t a3_ = QA(gnext + 3);                                      \
    asm volatile(                                                            \
      "ds_read_b128 %0, %8\n\t"                                              \
      "ds_read_b128 %1, %9\n\t"                                              \
      "ds_read_b128 %2, %10\n\t"                                             \
      "ds_read_b128 %3, %11\n\t"                                             \
      "ds_read_b128 %4, %12\n\t"                                             \
      "ds_read_b128 %5, %12 offset:16\n\t"                                   \
      "ds_read_b128 %6, %12 offset:32\n\t"                                   \
      "ds_read_b128 %7, %12 offset:48\n\t"                                   \
      "s_waitcnt lgkmcnt(0)"                                                 \
      : "=&v"(C0), "=&v"(C1), "=&v"(C2), "=&v"(C3),                          \
        "=&v"(k0), "=&v"(k1), "=&v"(k2), "=&v"(k3)                           \
      : "v"(a0_), "v"(a1_), "v"(a2_), "v"(a3_), "v"(kcur)                    \
      : "memory");                                                           \
    MAC4x8(A0, A1, A2, k0);                                                  \
    MAC4x8(A1, A2, A3, k1);                                                  \
    MAC4x8(A2, A3, B0, k2);                                                  \
    MAC4x8(A3, B0, B1, k3);                                                  \
    gnext += 4; kcur += 64;                                                  \
  } while (0)

__global__ __launch_bounds__(512, 4) void corr_topk_kernel(
    const float* __restrict__ Q, const float* __restrict__ K,
    float* __restrict__ ws_w, int* __restrict__ ws_i)
{
  __shared__ __align__(16) float qs[8][576];   // 18432 B: 144 phys groups/row
  __shared__ __align__(16) float ks[8][512];   // 16384 B, linear (total 34816)

  const int tid = threadIdx.x;
  const int bid = blockIdx.x;
  // chunked XCD remap: all 64 blocks of one bh on one XCD (L2 line merge)
  const int work = (bid & 7) * 1024 + (bid >> 3);
  const int bh   = work >> 6;
  const int c0   = (work & 63) * 8;

  const size_t base = (size_t)(bh >> 3) * (size_t)(L_LEN * D_DIM)
                    + (size_t)(bh & 7) * 512 + c0;

  // staging: thread loads float4 = 4 channels of one row t (store once,
  // no duplication; mod-128 group indexing in the hot loop handles wrap)
  #pragma unroll
  for (int rep = 0; rep < 2; ++rep) {
    const int idx  = rep * 512 + tid;       // 0..1023
    const int t    = idx >> 1;
    const int half = idx & 1;
    const float4 qv = *(const float4*)(Q + base + (size_t)t * D_DIM + half * 4);
    const float4 kv = *(const float4*)(K + base + (size_t)t * D_DIM + half * 4);
    const int g  = t >> 2;
    const int pw = ((g + (g >> 3)) << 2) | (t & 3);   // padded word index
    const int cb = half * 4;
    const float qa[4] = {qv.x, qv.y, qv.z, qv.w};
    const float ka[4] = {kv.x, kv.y, kv.z, kv.w};
    #pragma unroll
    for (int j = 0; j < 4; ++j) {
      qs[cb + j][pw] = qa[j];
      ks[cb + j][t]  = ka[j];
    }
  }
  __syncthreads();

  const int wv   = __builtin_amdgcn_readfirstlane(tid >> 6);
  const int lane = tid & 63;
  const int tau0 = lane * 8;
  const int gq   = lane * 2;                // logical group of tau0

  const uint32_t qbase = (uint32_t)(uintptr_t)(&qs[wv][0]);
  const uint32_t kbase = (uint32_t)(uintptr_t)(&ks[wv][0]);

  float acc0 = 0.f, acc1 = 0.f, acc2 = 0.f, acc3 = 0.f;
  float acc4 = 0.f, acc5 = 0.f, acc6 = 0.f, acc7 = 0.f;
  f32x4 wA0, wA1, wA2, wA3, wB0, wB1, wB2, wB3, wC0, wC1, wC2, wC3;
  f32x4 k0, k1, k2, k3;

  // prologue: window = groups gq..gq+7 (taus tau0..tau0+31)
  {
    const uint32_t p0 = QA(gq),     p1 = QA(gq + 1);
    const uint32_t p2 = QA(gq + 2), p3 = QA(gq + 3);
    const uint32_t p4 = QA(gq + 4), p5 = QA(gq + 5);
    const uint32_t p6 = QA(gq + 6), p7 = QA(gq + 7);
    asm volatile(
      "ds_read_b128 %0, %8\n\t"
      "ds_read_b128 %1, %9\n\t"
      "ds_read_b128 %2, %10\n\t"
      "ds_read_b128 %3, %11\n\t"
      "ds_read_b128 %4, %12\n\t"
      "ds_read_b128 %5, %13\n\t"
      "ds_read_b128 %6, %14\n\t"
      "ds_read_b128 %7, %15\n\t"
      "s_waitcnt lgkmcnt(0)"
      : "=&v"(wA0), "=&v"(wA1), "=&v"(wA2), "=&v"(wA3),
        "=&v"(wB0), "=&v"(wB1), "=&v"(wB2), "=&v"(wB3)
      : "v"(p0), "v"(p1), "v"(p2), "v"(p3), "v"(p4), "v"(p5), "v"(p6), "v"(p7)
      : "memory");
  }

  uint32_t gnext = (uint32_t)(gq + 8);
  uint32_t kcur  = kbase;

  // 32 ITERs total: 10x3 + 2 tail (period-3 register rotation)
  #pragma unroll 1
  for (int i = 0; i < 30; i += 3) {
    ITER3(wA0,wA1,wA2,wA3, wB0,wB1,wB2,wB3, wC0,wC1,wC2,wC3);
    ITER3(wB0,wB1,wB2,wB3, wC0,wC1,wC2,wC3, wA0,wA1,wA2,wA3);
    ITER3(wC0,wC1,wC2,wC3, wA0,wA1,wA2,wA3, wB0,wB1,wB2,wB3);
  }
  ITER3(wA0,wA1,wA2,wA3, wB0,wB1,wB2,wB3, wC0,wC1,wC2,wC3);  // I=30
  ITER3(wB0,wB1,wB2,wB3, wC0,wC1,wC2,wC3, wA0,wA1,wA2,wA3);  // I=31 (tail loads junk, unused)

  float acc[8] = {acc0, acc1, acc2, acc3, acc4, acc5, acc6, acc7};

  // ---- top-12 via repeated wave-wide argmax (tie-break: smaller index)
  float bv[TOPK]; int bi[TOPK];
  #pragma unroll
  for (int s = 0; s < TOPK; ++s) {
    float lv = acc[0]; int li = 0;
    #pragma unroll
    for (int i = 1; i < 8; ++i) if (acc[i] > lv) { lv = acc[i]; li = i; }
    int gi = tau0 + li;
    #pragma unroll
    for (int off = 32; off >= 1; off >>= 1) {
      const float ov = __shfl_xor(lv, off, 64);
      const int   oi = __shfl_xor(gi, off, 64);
      if (ov > lv || (ov == lv && oi < gi)) { lv = ov; gi = oi; }
    }
    bv[s] = lv; bi[s] = gi;
    const int slot = gi - tau0;
    #pragma unroll
    for (int i = 0; i < 8; ++i) acc[i] = (slot == i) ? -3.4e38f : acc[i];
  }

  float e[TOPK]; float sum = 0.f;
  #pragma unroll
  for (int s = 0; s < TOPK; ++s) { e[s] = expf(bv[s] - bv[0]); sum += e[s]; }
  const float inv = 1.f / sum;

  if (lane == 0) {
    const int g = (bh * 512 + c0 + wv) * TOPK;
    #pragma unroll
    for (int s = 0; s < TOPK; ++s) { ws_w[g + s] = e[s] * inv; ws_i[g + s] = bi[s]; }
  }
}

// ---------------------------------------------------------------------------
// Stage B (verbatim passing version, ~230 us): block = (b, 32-column window
// of D), 512 threads, vs staged in descending quarters (r = min(r0+t,511)
// >= t -> later stagings write strictly lower rows than any concurrent
// reader; 1 barrier/phase; next quarter's loads issued before the barrier,
// raw s_barrier keeps them in flight). LDS = 65536 B exactly.
// ---------------------------------------------------------------------------
__global__ __launch_bounds__(512, 4) void gather_kernel(
    const float* __restrict__ V, const float* __restrict__ ws_w,
    const int* __restrict__ ws_i, float* __restrict__ out)
{
  __shared__ __align__(16) float vs[512][32];   // 65536 B

  const int tid = threadIdx.x;
  const int bid = blockIdx.x;
  const int work = (bid & 7) * 256 + (bid >> 3);   // chunked XCD remap
  const int b  = work >> 7;
  const int dg = work & 127;
  const int d0 = dg * 32;
  const int h  = d0 >> 9;
  const int c0 = d0 & 511;

  const size_t vcol = (size_t)b * (size_t)(L_LEN * D_DIM) + d0;

  const int cl   = tid & 31;
  const int tsub = tid >> 5;              // 0..15

  float4 stga, stgb;
  const int e0 = tid, e1 = 512 + tid;
  const int ra0 = e0 >> 3, qa0 = (e0 & 7) * 4;   // rows 0..63 of quarter
  const int rb0 = e1 >> 3, qb0 = (e1 & 7) * 4;   // rows 64..127 of quarter

  // prologue: issue loads for phase 3 (rows 384..511)
  stga = *(const float4*)(V + vcol + (size_t)(384 + ra0) * D_DIM + qa0);
  stgb = *(const float4*)(V + vcol + (size_t)(384 + rb0) * D_DIM + qb0);

  const int g = ((b * 8 + h) * 512 + c0 + cl) * TOPK;
  float w[TOPK]; int r0[TOPK];
  #pragma unroll
  for (int s = 0; s < TOPK; ++s) { w[s] = ws_w[g + s]; r0[s] = ws_i[g + s]; }

  const size_t ob = vcol + cl;

  #pragma unroll 1
  for (int ph = 3; ph >= 0; --ph) {
    *(float4*)(&vs[ph * 128 + ra0][qa0]) = stga;
    *(float4*)(&vs[ph * 128 + rb0][qb0]) = stgb;
    if (ph > 0) {  // issue next quarter early; in flight across the barrier
      stga = *(const float4*)(V + vcol + (size_t)((ph - 1) * 128 + ra0) * D_DIM + qa0);
      stgb = *(const float4*)(V + vcol + (size_t)((ph - 1) * 128 + rb0) * D_DIM + qb0);
    }
    asm volatile("s_waitcnt lgkmcnt(0)" ::: "memory");
    __builtin_amdgcn_s_barrier();
    asm volatile("" ::: "memory");

    // compute outputs t in [ph*128, (ph+1)*128)
    #pragma unroll
    for (int k8 = 0; k8 < 8; ++k8) {
      const int t = ph * 128 + (k8 << 4) + tsub;
      float a = 0.f;
      #pragma unroll
      for (int s = 0; s < TOPK; ++s) {
        int r = r0[s] + t;
        r = r > (L_LEN - 1) ? (L_LEN - 1) : r;
        a = fmaf(w[s], vs[r][cl], a);       // bank = cl: scatter-immune
      }
      out[ob + (size_t)t * D_DIM] = a;
    }
  }
}

extern "C" void kernel_launch(void* const* d_in, const int* in_sizes, int n_in,
                              void* d_out, int out_size, void* d_ws, size_t ws_size,
                              hipStream_t stream)
{
  const float* Q = (const float*)d_in[0];
  const float* K = (const float*)d_in[1];
  const float* V = (const float*)d_in[2];
  float* out = (float*)d_out;

  float* ws_w = (float*)d_ws;
  int*   ws_i = (int*)((char*)d_ws + (size_t)B_NUM * H_NUM * 512 * TOPK * sizeof(float));

  corr_topk_kernel<<<dim3(B_NUM * H_NUM * 64), dim3(512), 0, stream>>>(Q, K, ws_w, ws_i);
  gather_kernel<<<dim3(B_NUM * H_NUM * 16), dim3(512), 0, stream>>>(V, ws_w, ws_i, out);
}

// Round 8
// 765.301 us; speedup vs baseline: 1.1323x; 1.0934x over previous
//
#include <hip/hip_runtime.h>
#include <stdint.h>

#define L_LEN 512
#define D_DIM 4096
#define H_NUM 8
#define B_NUM 16
#define TOPK  12

typedef float f32x4 __attribute__((ext_vector_type(4)));

// ---------------------------------------------------------------------------
// Stage A: per-channel circular cross-correlation + top-12 + softmax.
// grid = B*H*64 blocks of 256 threads = 4 waves; ONE channel per 32-lane
// HALF-WAVE (2 ch/wave, 8 ch/block). Lane (m = lane&31) owns taus
// 16m..16m+15. Per 16-t step: 8 q b128 + 4 k b128 (half-wave-uniform
// broadcast) feed 256 FMAs — 2x the FMA/LDS-op density of the r7 kernel
// (junk-VALU tracked LDS-read count across r1/r4/r7).
// q LDS layout: 16B group G at physical group G + (G>>3) (pad 1 per 8):
// lane m reads G = 4m + c; every 8 consecutive lanes cover all 8
// bank-groups for every c (enumerated) -> conflict-free ds_read_b128.
// All hot-loop reads are inline-asm ds_read_b128 (hipcc scalarizes C-level
// float4 LDS reads; r4/r6 evidence). Window = 12 named f32x4, period-3.
// ---------------------------------------------------------------------------

// physical byte address (within channel row) of logical 16B group G
#define QA(G) (qbase + (((((uint32_t)(G)) & 127u) + ((((uint32_t)(G)) & 127u) >> 3)) << 4))

// 64 FMAs: acc[i] += q[i+t]*k[t], t = 0..3 of this k-quad; window quads
// QA_..QE_ hold taus [w, w+20) relative to acc0's tau at this t0.
#define MAC4x16(QA_, QB_, QC_, QD_, QE_, KK_) do {                            \
    acc0  = fmaf(QA_.x, KK_.x, acc0);  acc0  = fmaf(QA_.y, KK_.y, acc0);      \
    acc0  = fmaf(QA_.z, KK_.z, acc0);  acc0  = fmaf(QA_.w, KK_.w, acc0);      \
    acc1  = fmaf(QA_.y, KK_.x, acc1);  acc1  = fmaf(QA_.z, KK_.y, acc1);      \
    acc1  = fmaf(QA_.w, KK_.z, acc1);  acc1  = fmaf(QB_.x, KK_.w, acc1);      \
    acc2  = fmaf(QA_.z, KK_.x, acc2);  acc2  = fmaf(QA_.w, KK_.y, acc2);      \
    acc2  = fmaf(QB_.x, KK_.z, acc2);  acc2  = fmaf(QB_.y, KK_.w, acc2);      \
    acc3  = fmaf(QA_.w, KK_.x, acc3);  acc3  = fmaf(QB_.x, KK_.y, acc3);      \
    acc3  = fmaf(QB_.y, KK_.z, acc3);  acc3  = fmaf(QB_.z, KK_.w, acc3);      \
    acc4  = fmaf(QB_.x, KK_.x, acc4);  acc4  = fmaf(QB_.y, KK_.y, acc4);      \
    acc4  = fmaf(QB_.z, KK_.z, acc4);  acc4  = fmaf(QB_.w, KK_.w, acc4);      \
    acc5  = fmaf(QB_.y, KK_.x, acc5);  acc5  = fmaf(QB_.z, KK_.y, acc5);      \
    acc5  = fmaf(QB_.w, KK_.z, acc5);  acc5  = fmaf(QC_.x, KK_.w, acc5);      \
    acc6  = fmaf(QB_.z, KK_.x, acc6);  acc6  = fmaf(QB_.w, KK_.y, acc6);      \
    acc6  = fmaf(QC_.x, KK_.z, acc6);  acc6  = fmaf(QC_.y, KK_.w, acc6);      \
    acc7  = fmaf(QB_.w, KK_.x, acc7);  acc7  = fmaf(QC_.x, KK_.y, acc7);      \
    acc7  = fmaf(QC_.y, KK_.z, acc7);  acc7  = fmaf(QC_.z, KK_.w, acc7);      \
    acc8  = fmaf(QC_.x, KK_.x, acc8);  acc8  = fmaf(QC_.y, KK_.y, acc8);      \
    acc8  = fmaf(QC_.z, KK_.z, acc8);  acc8  = fmaf(QC_.w, KK_.w, acc8);      \
    acc9  = fmaf(QC_.y, KK_.x, acc9);  acc9  = fmaf(QC_.z, KK_.y, acc9);      \
    acc9  = fmaf(QC_.w, KK_.z, acc9);  acc9  = fmaf(QD_.x, KK_.w, acc9);      \
    acc10 = fmaf(QC_.z, KK_.x, acc10); acc10 = fmaf(QC_.w, KK_.y, acc10);     \
    acc10 = fmaf(QD_.x, KK_.z, acc10); acc10 = fmaf(QD_.y, KK_.w, acc10);     \
    acc11 = fmaf(QC_.w, KK_.x, acc11); acc11 = fmaf(QD_.x, KK_.y, acc11);     \
    acc11 = fmaf(QD_.y, KK_.z, acc11); acc11 = fmaf(QD_.z, KK_.w, acc11);     \
    acc12 = fmaf(QD_.x, KK_.x, acc12); acc12 = fmaf(QD_.y, KK_.y, acc12);     \
    acc12 = fmaf(QD_.z, KK_.z, acc12); acc12 = fmaf(QD_.w, KK_.w, acc12);     \
    acc13 = fmaf(QD_.y, KK_.x, acc13); acc13 = fmaf(QD_.z, KK_.y, acc13);     \
    acc13 = fmaf(QD_.w, KK_.z, acc13); acc13 = fmaf(QE_.x, KK_.w, acc13);     \
    acc14 = fmaf(QD_.z, KK_.x, acc14); acc14 = fmaf(QD_.w, KK_.y, acc14);     \
    acc14 = fmaf(QE_.x, KK_.z, acc14); acc14 = fmaf(QE_.y, KK_.w, acc14);     \
    acc15 = fmaf(QD_.w, KK_.x, acc15); acc15 = fmaf(QE_.x, KK_.y, acc15);     \
    acc15 = fmaf(QE_.y, KK_.z, acc15); acc15 = fmaf(QE_.z, KK_.w, acc15);     \
  } while (0)

// One 16-t step: window (A0..A3,B0..B3) = groups [gnext-8, gnext);
// loads next 4 q groups into C0..C3 and 16 k floats into k0..k3.
#define ITERX(A0,A1,A2,A3, B0,B1,B2,B3, C0,C1,C2,C3) do {                    \
    const uint32_t a0_ = QA(gnext);                                          \
    const uint32_t a1_ = QA(gnext + 1);                                      \
    const uint32_t a2_ = QA(gnext + 2);                                      \
    const uint32_t a3_ = QA(gnext + 3);                                      \
    asm volatile(                                                            \
      "ds_read_b128 %0, %8\n\t"                                              \
      "ds_read_b128 %1, %9\n\t"                                              \
      "ds_read_b128 %2, %10\n\t"                                             \
      "ds_read_b128 %3, %11\n\t"                                             \
      "ds_read_b128 %4, %12\n\t"                                             \
      "ds_read_b128 %5, %12 offset:16\n\t"                                   \
      "ds_read_b128 %6, %12 offset:32\n\t"                                   \
      "ds_read_b128 %7, %12 offset:48\n\t"                                   \
      "s_waitcnt lgkmcnt(0)"                                                 \
      : "=&v"(C0), "=&v"(C1), "=&v"(C2), "=&v"(C3),                          \
        "=&v"(k0), "=&v"(k1), "=&v"(k2), "=&v"(k3)                           \
      : "v"(a0_), "v"(a1_), "v"(a2_), "v"(a3_), "v"(kptr)                    \
      : "memory");                                                           \
    MAC4x16(A0, A1, A2, A3, B0, k0);                                         \
    MAC4x16(A1, A2, A3, B0, B1, k1);                                         \
    MAC4x16(A2, A3, B0, B1, B2, k2);                                         \
    MAC4x16(A3, B0, B1, B2, B3, k3);                                         \
    gnext += 4; kptr += 64;                                                  \
  } while (0)

__global__ __launch_bounds__(256, 4) void corr_topk_kernel(
    const float* __restrict__ Q, const float* __restrict__ K,
    float* __restrict__ ws_w, int* __restrict__ ws_i)
{
  __shared__ __align__(16) float qs[8][576];   // 18432 B: 144 phys groups/row
  __shared__ __align__(16) float ks[8][512];   // 16384 B, linear (total 34816)

  const int tid = threadIdx.x;
  const int bid = blockIdx.x;
  // chunked XCD remap: all 64 blocks of one bh on one XCD (L2 line merge)
  const int work = (bid & 7) * 1024 + (bid >> 3);
  const int bh   = work >> 6;
  const int c0   = (work & 63) * 8;

  const size_t base = (size_t)(bh >> 3) * (size_t)(L_LEN * D_DIM)
                    + (size_t)(bh & 7) * 512 + c0;

  // staging (r1-proven 4-rep pattern, r7-proven pad layout)
  #pragma unroll
  for (int rep = 0; rep < 4; ++rep) {
    const int idx  = rep * 256 + tid;       // 0..1023
    const int t    = idx >> 1;
    const int half = idx & 1;
    const float4 qv = *(const float4*)(Q + base + (size_t)t * D_DIM + half * 4);
    const float4 kv = *(const float4*)(K + base + (size_t)t * D_DIM + half * 4);
    const int g  = t >> 2;
    const int pw = ((g + (g >> 3)) << 2) | (t & 3);   // padded word index
    const int cb = half * 4;
    const float qa[4] = {qv.x, qv.y, qv.z, qv.w};
    const float ka[4] = {kv.x, kv.y, kv.z, kv.w};
    #pragma unroll
    for (int j = 0; j < 4; ++j) {
      qs[cb + j][pw] = qa[j];
      ks[cb + j][t]  = ka[j];
    }
  }
  __syncthreads();

  const int wv   = tid >> 6;
  const int lane = tid & 63;
  const int m    = lane & 31;               // tau index within channel
  const int ch   = wv * 2 + (lane >> 5);    // channel of this half-wave
  const int tau0 = m * 16;
  const int gq   = m * 4;                   // logical group of tau0

  const uint32_t qbase = (uint32_t)(uintptr_t)(&qs[ch][0]);
  uint32_t       kptr  = (uint32_t)(uintptr_t)(&ks[ch][0]);

  float acc0  = 0.f, acc1  = 0.f, acc2  = 0.f, acc3  = 0.f;
  float acc4  = 0.f, acc5  = 0.f, acc6  = 0.f, acc7  = 0.f;
  float acc8  = 0.f, acc9  = 0.f, acc10 = 0.f, acc11 = 0.f;
  float acc12 = 0.f, acc13 = 0.f, acc14 = 0.f, acc15 = 0.f;
  f32x4 wA0, wA1, wA2, wA3, wB0, wB1, wB2, wB3, wC0, wC1, wC2, wC3;
  f32x4 k0, k1, k2, k3;

  // prologue: window = groups gq..gq+7 (taus tau0..tau0+31, circular)
  {
    const uint32_t p0 = QA(gq),     p1 = QA(gq + 1);
    const uint32_t p2 = QA(gq + 2), p3 = QA(gq + 3);
    const uint32_t p4 = QA(gq + 4), p5 = QA(gq + 5);
    const uint32_t p6 = QA(gq + 6), p7 = QA(gq + 7);
    asm volatile(
      "ds_read_b128 %0, %8\n\t"
      "ds_read_b128 %1, %9\n\t"
      "ds_read_b128 %2, %10\n\t"
      "ds_read_b128 %3, %11\n\t"
      "ds_read_b128 %4, %12\n\t"
      "ds_read_b128 %5, %13\n\t"
      "ds_read_b128 %6, %14\n\t"
      "ds_read_b128 %7, %15\n\t"
      "s_waitcnt lgkmcnt(0)"
      : "=&v"(wA0), "=&v"(wA1), "=&v"(wA2), "=&v"(wA3),
        "=&v"(wB0), "=&v"(wB1), "=&v"(wB2), "=&v"(wB3)
      : "v"(p0), "v"(p1), "v"(p2), "v"(p3), "v"(p4), "v"(p5), "v"(p6), "v"(p7)
      : "memory");
  }

  uint32_t gnext = (uint32_t)(gq + 8);

  // 32 steps of 16 t: 10x3 + 2 tail (period-3 register rotation)
  #pragma unroll 1
  for (int i = 0; i < 30; i += 3) {
    ITERX(wA0,wA1,wA2,wA3, wB0,wB1,wB2,wB3, wC0,wC1,wC2,wC3);
    ITERX(wB0,wB1,wB2,wB3, wC0,wC1,wC2,wC3, wA0,wA1,wA2,wA3);
    ITERX(wC0,wC1,wC2,wC3, wA0,wA1,wA2,wA3, wB0,wB1,wB2,wB3);
  }
  ITERX(wA0,wA1,wA2,wA3, wB0,wB1,wB2,wB3, wC0,wC1,wC2,wC3);  // step 30
  ITERX(wB0,wB1,wB2,wB3, wC0,wC1,wC2,wC3, wA0,wA1,wA2,wA3);  // step 31 (tail loads junk)

  float acc[16] = {acc0, acc1, acc2,  acc3,  acc4,  acc5,  acc6,  acc7,
                   acc8, acc9, acc10, acc11, acc12, acc13, acc14, acc15};

  // ---- top-12 via repeated argmax over the 32-lane channel group (r1-proven)
  float bv[TOPK]; int bi[TOPK];
  #pragma unroll
  for (int s = 0; s < TOPK; ++s) {
    float lv = acc[0]; int li = 0;
    #pragma unroll
    for (int i = 1; i < 16; ++i) if (acc[i] > lv) { lv = acc[i]; li = i; }
    int gi = tau0 + li;
    #pragma unroll
    for (int off = 16; off >= 1; off >>= 1) {
      const float ov = __shfl_xor(lv, off, 32);
      const int   oi = __shfl_xor(gi, off, 32);
      if (ov > lv || (ov == lv && oi < gi)) { lv = ov; gi = oi; }
    }
    bv[s] = lv; bi[s] = gi;
    const int slot = gi - tau0;
    #pragma unroll
    for (int i = 0; i < 16; ++i) acc[i] = (slot == i) ? -3.4e38f : acc[i];
  }

  float e[TOPK]; float sum = 0.f;
  #pragma unroll
  for (int s = 0; s < TOPK; ++s) { e[s] = expf(bv[s] - bv[0]); sum += e[s]; }
  const float inv = 1.f / sum;

  if (m == 0) {
    const int g = (bh * 512 + c0 + ch) * TOPK;
    #pragma unroll
    for (int s = 0; s < TOPK; ++s) { ws_w[g + s] = e[s] * inv; ws_i[g + s] = bi[s]; }
  }
}

// ---------------------------------------------------------------------------
// Stage B (verbatim passing version, ~215 us): block = (b, 32-column window
// of D), 512 threads, vs staged in descending quarters (r = min(r0+t,511)
// >= t -> later stagings write strictly lower rows than any concurrent
// reader; 1 barrier/phase; next quarter's loads issued before the barrier,
// raw s_barrier keeps them in flight). LDS = 65536 B exactly.
// ---------------------------------------------------------------------------
__global__ __launch_bounds__(512, 4) void gather_kernel(
    const float* __restrict__ V, const float* __restrict__ ws_w,
    const int* __restrict__ ws_i, float* __restrict__ out)
{
  __shared__ __align__(16) float vs[512][32];   // 65536 B

  const int tid = threadIdx.x;
  const int bid = blockIdx.x;
  const int work = (bid & 7) * 256 + (bid >> 3);   // chunked XCD remap
  const int b  = work >> 7;
  const int dg = work & 127;
  const int d0 = dg * 32;
  const int h  = d0 >> 9;
  const int c0 = d0 & 511;

  const size_t vcol = (size_t)b * (size_t)(L_LEN * D_DIM) + d0;

  const int cl   = tid & 31;
  const int tsub = tid >> 5;              // 0..15

  float4 stga, stgb;
  const int e0 = tid, e1 = 512 + tid;
  const int ra0 = e0 >> 3, qa0 = (e0 & 7) * 4;   // rows 0..63 of quarter
  const int rb0 = e1 >> 3, qb0 = (e1 & 7) * 4;   // rows 64..127 of quarter

  // prologue: issue loads for phase 3 (rows 384..511)
  stga = *(const float4*)(V + vcol + (size_t)(384 + ra0) * D_DIM + qa0);
  stgb = *(const float4*)(V + vcol + (size_t)(384 + rb0) * D_DIM + qb0);

  const int g = ((b * 8 + h) * 512 + c0 + cl) * TOPK;
  float w[TOPK]; int r0[TOPK];
  #pragma unroll
  for (int s = 0; s < TOPK; ++s) { w[s] = ws_w[g + s]; r0[s] = ws_i[g + s]; }

  const size_t ob = vcol + cl;

  #pragma unroll 1
  for (int ph = 3; ph >= 0; --ph) {
    *(float4*)(&vs[ph * 128 + ra0][qa0]) = stga;
    *(float4*)(&vs[ph * 128 + rb0][qb0]) = stgb;
    if (ph > 0) {  // issue next quarter early; in flight across the barrier
      stga = *(const float4*)(V + vcol + (size_t)((ph - 1) * 128 + ra0) * D_DIM + qa0);
      stgb = *(const float4*)(V + vcol + (size_t)((ph - 1) * 128 + rb0) * D_DIM + qb0);
    }
    asm volatile("s_waitcnt lgkmcnt(0)" ::: "memory");
    __builtin_amdgcn_s_barrier();
    asm volatile("" ::: "memory");

    // compute outputs t in [ph*128, (ph+1)*128)
    #pragma unroll
    for (int k8 = 0; k8 < 8; ++k8) {
      const int t = ph * 128 + (k8 << 4) + tsub;
      float a = 0.f;
      #pragma unroll
      for (int s = 0; s < TOPK; ++s) {
        int r = r0[s] + t;
        r = r > (L_LEN - 1) ? (L_LEN - 1) : r;
        a = fmaf(w[s], vs[r][cl], a);       // bank = cl: scatter-immune
      }
      out[ob + (size_t)t * D_DIM] = a;
    }
  }
}

extern "C" void kernel_launch(void* const* d_in, const int* in_sizes, int n_in,
                              void* d_out, int out_size, void* d_ws, size_t ws_size,
                              hipStream_t stream)
{
  const float* Q = (const float*)d_in[0];
  const float* K = (const float*)d_in[1];
  const float* V = (const float*)d_in[2];
  float* out = (float*)d_out;

  float* ws_w = (float*)d_ws;
  int*   ws_i = (int*)((char*)d_ws + (size_t)B_NUM * H_NUM * 512 * TOPK * sizeof(float));

  corr_topk_kernel<<<dim3(B_NUM * H_NUM * 64), dim3(256), 0, stream>>>(Q, K, ws_w, ws_i);
  gather_kernel<<<dim3(B_NUM * H_NUM * 16), dim3(512), 0, stream>>>(V, ws_w, ws_i, out);
}